// Round 1
// baseline (660.586 us; speedup 1.0000x reference)
//
#include <hip/hip_runtime.h>
#include <hip/hip_bf16.h>

#define PROPOSALS_PER_IM 300
#define HUBER_T 3.0f

__global__ __launch_bounds__(256) void _RPN_71459665871443_kernel(
        const float* __restrict__ output,      // (B*300, 8)
        const float* __restrict__ gt_boxes,    // (B, 4)
        const int*   __restrict__ central_pos, // (B,)
        float* __restrict__ loss_out,          // (1,) pre-zeroed
        int B, float inv_n) {
    int i = blockIdx.x * blockDim.x + threadIdx.x;
    float s = 0.0f;
    if (i < B) {
        long long row = (long long)i * PROPOSALS_PER_IM + (long long)central_pos[i];
        // pred_box = output[row, 4:8]; byte offset = 32*row + 16 -> 16B aligned
        const float4 p = *reinterpret_cast<const float4*>(output + row * 8 + 4);
        const float4 g = *reinterpret_cast<const float4*>(gt_boxes + (size_t)i * 4);

        float d0 = p.x - g.x, d1 = p.y - g.y, d2 = p.z - g.z, d3 = p.w - g.w;
        float a0 = fabsf(d0), a1 = fabsf(d1), a2 = fabsf(d2), a3 = fabsf(d3);
        s  = (a0 < HUBER_T) ? d0 * d0 : a0;
        s += (a1 < HUBER_T) ? d1 * d1 : a1;
        s += (a2 < HUBER_T) ? d2 * d2 : a2;
        s += (a3 < HUBER_T) ? d3 * d3 : a3;
    }

    // wave64 butterfly reduce
    #pragma unroll
    for (int off = 32; off > 0; off >>= 1)
        s += __shfl_down(s, off, 64);

    __shared__ float warp_sums[4];  // 256 threads = 4 waves
    int lane = threadIdx.x & 63;
    int wave = threadIdx.x >> 6;
    if (lane == 0) warp_sums[wave] = s;
    __syncthreads();

    if (threadIdx.x == 0) {
        float blk = warp_sums[0] + warp_sums[1] + warp_sums[2] + warp_sums[3];
        atomicAdd(loss_out, blk * inv_n);
    }
}

extern "C" void kernel_launch(void* const* d_in, const int* in_sizes, int n_in,
                              void* d_out, int out_size, void* d_ws, size_t ws_size,
                              hipStream_t stream) {
    const float* output      = (const float*)d_in[0];
    const float* gt_boxes    = (const float*)d_in[1];
    const int*   central_pos = (const int*)d_in[2];
    float* loss = (float*)d_out;

    int B = in_sizes[1] / 4;           // gt_boxes has B*4 elements
    float inv_n = 1.0f / (4.0f * (float)B);

    // d_out is poisoned to 0xAA before every call; zero it (capture-safe).
    hipMemsetAsync(loss, 0, sizeof(float), stream);

    int block = 256;
    int grid = (B + block - 1) / block;  // 256 blocks for B=65536
    _RPN_71459665871443_kernel<<<grid, block, 0, stream>>>(
        output, gt_boxes, central_pos, loss, B, inv_n);
}

// Round 2
// 659.307 us; speedup vs baseline: 1.0019x; 1.0019x over previous
//
#include <hip/hip_runtime.h>
#include <hip/hip_bf16.h>

#define PROPOSALS_PER_IM 300
#define HUBER_T 3.0f

// Kernel 1: each block of 256 threads handles 256 images; writes its partial
// sum (pre-scaled by 1/N) to d_ws[blockIdx]. Every slot [0..gridDim) is
// written, so the 0xAA-poisoned workspace needs no zero-init.
__global__ __launch_bounds__(256) void _RPN_71459665871443_partial(
        const float* __restrict__ output,      // (B*300, 8)
        const float* __restrict__ gt_boxes,    // (B, 4)
        const int*   __restrict__ central_pos, // (B,)
        float* __restrict__ partials,          // (gridDim.x,)
        int B, float inv_n) {
    int i = blockIdx.x * blockDim.x + threadIdx.x;
    float s = 0.0f;
    if (i < B) {
        long long row = (long long)i * PROPOSALS_PER_IM + (long long)central_pos[i];
        // pred_box = output[row, 4:8]; byte offset = 32*row + 16 -> 16B aligned
        const float4 p = *reinterpret_cast<const float4*>(output + row * 8 + 4);
        const float4 g = *reinterpret_cast<const float4*>(gt_boxes + (size_t)i * 4);

        float d0 = p.x - g.x, d1 = p.y - g.y, d2 = p.z - g.z, d3 = p.w - g.w;
        float a0 = fabsf(d0), a1 = fabsf(d1), a2 = fabsf(d2), a3 = fabsf(d3);
        s  = (a0 < HUBER_T) ? d0 * d0 : a0;
        s += (a1 < HUBER_T) ? d1 * d1 : a1;
        s += (a2 < HUBER_T) ? d2 * d2 : a2;
        s += (a3 < HUBER_T) ? d3 * d3 : a3;
    }

    // wave64 butterfly reduce
    #pragma unroll
    for (int off = 32; off > 0; off >>= 1)
        s += __shfl_down(s, off, 64);

    __shared__ float warp_sums[4];  // 256 threads = 4 waves
    int lane = threadIdx.x & 63;
    int wave = threadIdx.x >> 6;
    if (lane == 0) warp_sums[wave] = s;
    __syncthreads();

    if (threadIdx.x == 0) {
        float blk = warp_sums[0] + warp_sums[1] + warp_sums[2] + warp_sums[3];
        partials[blockIdx.x] = blk * inv_n;
    }
}

// Kernel 2: one block sums the 256 partials -> d_out. Kernel-boundary
// ordering on the stream guarantees visibility of kernel 1's writes.
__global__ __launch_bounds__(256) void _RPN_71459665871443_final(
        const float* __restrict__ partials, float* __restrict__ loss_out, int n) {
    float s = (threadIdx.x < n) ? partials[threadIdx.x] : 0.0f;

    #pragma unroll
    for (int off = 32; off > 0; off >>= 1)
        s += __shfl_down(s, off, 64);

    __shared__ float warp_sums[4];
    int lane = threadIdx.x & 63;
    int wave = threadIdx.x >> 6;
    if (lane == 0) warp_sums[wave] = s;
    __syncthreads();

    if (threadIdx.x == 0)
        loss_out[0] = warp_sums[0] + warp_sums[1] + warp_sums[2] + warp_sums[3];
}

extern "C" void kernel_launch(void* const* d_in, const int* in_sizes, int n_in,
                              void* d_out, int out_size, void* d_ws, size_t ws_size,
                              hipStream_t stream) {
    const float* output      = (const float*)d_in[0];
    const float* gt_boxes    = (const float*)d_in[1];
    const int*   central_pos = (const int*)d_in[2];
    float* loss     = (float*)d_out;
    float* partials = (float*)d_ws;

    int B = in_sizes[1] / 4;           // gt_boxes has B*4 elements
    float inv_n = 1.0f / (4.0f * (float)B);

    int block = 256;
    int grid = (B + block - 1) / block;  // 256 blocks for B=65536

    _RPN_71459665871443_partial<<<grid, block, 0, stream>>>(
        output, gt_boxes, central_pos, partials, B, inv_n);
    _RPN_71459665871443_final<<<1, block, 0, stream>>>(partials, loss, grid);
}